// Round 2
// baseline (625.682 us; speedup 1.0000x reference)
//
#include <hip/hip_runtime.h>
#include <stdint.h>

#define BB 16
#define SS 2048
#define DD 128

typedef __attribute__((ext_vector_type(8))) short short8;
typedef __attribute__((ext_vector_type(4))) short short4v;
typedef __attribute__((ext_vector_type(4))) float float4v;

__device__ __forceinline__ short f2b(float f){
  unsigned u = __float_as_uint(f);
  u += 0x7fffu + ((u >> 16) & 1u);          // RNE
  return (short)(u >> 16);
}
__device__ __forceinline__ float b2f(short h){
  return __uint_as_float(((unsigned)(unsigned short)h) << 16);
}

// K (fp32, [b][k][d]) -> bf16 same layout
__global__ __launch_bounds__(256) void cvt_k(const float* __restrict__ k, short* __restrict__ kb){
  int i = blockIdx.x * 256 + threadIdx.x;
  float4v f = ((const float4v*)k)[i];
  short4v h;
  h[0]=f2b(f[0]); h[1]=f2b(f[1]); h[2]=f2b(f[2]); h[3]=f2b(f[3]);
  ((short4v*)kb)[i] = h;
}

// V (fp32, [b][k][d]) -> bf16 transposed [b][d][k]
__global__ __launch_bounds__(256) void trans_v(const float* __restrict__ v, short* __restrict__ vt){
  __shared__ float tile[32][33];
  int blk = blockIdx.x;
  int b   = blk >> 8;
  int rem = blk & 255;
  int k0 = (rem >> 2) << 5;
  int d0 = (rem & 3) << 5;
  int r = threadIdx.x >> 5, c = threadIdx.x & 31;
  const float* vb = v + (size_t)b * SS * DD;
  #pragma unroll
  for (int i=0;i<4;i++)
    tile[r + 8*i][c] = vb[(size_t)(k0 + r + 8*i) * DD + d0 + c];
  __syncthreads();
  short* vtb = vt + (size_t)b * DD * SS;
  #pragma unroll
  for (int i=0;i<4;i++)
    vtb[(size_t)(d0 + r + 8*i) * SS + k0 + c] = f2b(tile[c][r + 8*i]);
}

// Block = 64 Q-rows of one batch. 8 waves (512 thr). Grid = 512 (all co-resident, 2/CU).
// No global->LDS staging: K and Vt B-fragments are read directly from global
// (per load instr: 16 rows x one full 64B line -> perfectly coalesced).
// Pass A: S=QK^T row sums (barrier-free). Pass B: recompute S, write attention,
// LDS-bounce E into A-layout, PV from global Vt.
__global__ __launch_bounds__(512, 4) void attn(const float* __restrict__ q,
                                               const short* __restrict__ kb,
                                               const short* __restrict__ vt,
                                               float* __restrict__ out){
  __shared__ __align__(16) short P[64 * 136];   // E tile (64 rows x 128 keys), pad 8
  __shared__ float sums2[64][2];
  __shared__ float invl[64];

  const float scale = 0.08838834764831845f;     // 1/sqrt(128)
  int x = blockIdx.x;
  int b  = (x & 7) * 2 + (x >> 8);              // 2 batches per XCD (assuming XCD = blk%8)
  int q0 = ((x >> 3) & 31) << 6;
  int tid = threadIdx.x;
  int w = tid >> 6, L = tid & 63;
  int m = L & 15, quad = L >> 4;
  int rw = w & 3;                                // row-group: rows rw*16..+16
  int cw = w >> 2;                               // col-half: cols cw*64..+64

  const short* KbB = kb + (size_t)b * SS * DD;
  const short* VtB = vt + (size_t)b * DD * SS;

  // Q A-fragments for this wave's 16 rows (held all kernel)
  short8 aq[4];
  {
    const float* qrow = q + (size_t)(b * SS + q0 + rw * 16 + m) * DD;
    #pragma unroll
    for (int ks=0; ks<4; ks++){
      short8 h;
      #pragma unroll
      for (int j=0;j<8;j++) h[j] = f2b(qrow[ks*32 + quad*8 + j]);
      aq[ks] = h;
    }
  }

  // ---- Pass A: row sums of exp(S*scale), no barriers ----
  float rp[4] = {0.f, 0.f, 0.f, 0.f};
  for (int kt=0; kt<16; kt++){
    int n0 = kt*128 + cw*64;
    #pragma unroll
    for (int c=0;c<4;c++){
      const short* krow = KbB + (size_t)(n0 + c*16 + m) * DD + quad*8;
      float4v s = {0.f,0.f,0.f,0.f};
      #pragma unroll
      for (int ks=0; ks<4; ks++){
        short8 bk = *(const short8*)(krow + ks*32);
        s = __builtin_amdgcn_mfma_f32_16x16x32_bf16(aq[ks], bk, s, 0,0,0);
      }
      #pragma unroll
      for (int r=0;r<4;r++) rp[r] += __expf(s[r] * scale);
    }
  }
  #pragma unroll
  for (int off=1; off<16; off<<=1){
    #pragma unroll
    for (int r=0;r<4;r++) rp[r] += __shfl_xor(rp[r], off);
  }
  if (m == 0){
    #pragma unroll
    for (int r=0;r<4;r++) sums2[rw*16 + quad*4 + r][cw] = rp[r];
  }
  __syncthreads();
  if (tid < 64) invl[tid] = 1.0f / (sums2[tid][0] + sums2[tid][1]);
  __syncthreads();

  // ---- Pass B: recompute S, write attention, PV ----
  float* ctx = out;
  float* attRow = out + (size_t)BB * SS * DD + (size_t)(b * SS + q0) * SS;
  float4v oacc[4] = {{0.f,0.f,0.f,0.f},{0.f,0.f,0.f,0.f},{0.f,0.f,0.f,0.f},{0.f,0.f,0.f,0.f}};

  for (int kt=0; kt<16; kt++){
    int k0 = kt * 128;
    #pragma unroll
    for (int c=0;c<4;c++){
      const short* krow = KbB + (size_t)(k0 + cw*64 + c*16 + m) * DD + quad*8;
      float4v s = {0.f,0.f,0.f,0.f};
      #pragma unroll
      for (int ks=0; ks<4; ks++){
        short8 bk = *(const short8*)(krow + ks*32);
        s = __builtin_amdgcn_mfma_f32_16x16x32_bf16(aq[ks], bk, s, 0,0,0);
      }
      int col = cw*64 + c*16 + m;
      #pragma unroll
      for (int r=0;r<4;r++){
        int row = rw*16 + quad*4 + r;
        float ev = __expf(s[r] * scale);
        attRow[(size_t)row * SS + k0 + col] = ev * invl[row];
        P[row * 136 + col] = f2b(ev);
      }
    }
    __syncthreads();
    // PV: O += E @ V   (A-frags from LDS, B-frags direct from global Vt)
    short8 ap[4];
    #pragma unroll
    for (int ks=0; ks<4; ks++)
      ap[ks] = *(const short8*)&P[(rw*16 + m) * 136 + ks*32 + quad*8];
    #pragma unroll
    for (int c=0;c<4;c++){
      const short* vrow = VtB + (size_t)(cw*64 + c*16 + m) * SS + k0 + quad*8;
      #pragma unroll
      for (int ks=0; ks<4; ks++){
        short8 bv = *(const short8*)(vrow + ks*32);
        oacc[c] = __builtin_amdgcn_mfma_f32_16x16x32_bf16(ap[ks], bv, oacc[c], 0,0,0);
      }
    }
    __syncthreads();
  }

  #pragma unroll
  for (int c=0;c<4;c++){
    #pragma unroll
    for (int r=0;r<4;r++){
      int row = rw*16 + quad*4 + r;
      ctx[(size_t)(b * SS + q0 + row) * DD + cw*64 + c*16 + m] = oacc[c][r] * invl[row];
    }
  }
}

extern "C" void kernel_launch(void* const* d_in, const int* in_sizes, int n_in,
                              void* d_out, int out_size, void* d_ws, size_t ws_size,
                              hipStream_t stream) {
  const float* q = (const float*)d_in[0];
  const float* k = (const float*)d_in[1];
  const float* v = (const float*)d_in[2];
  float* out = (float*)d_out;
  short* kbf = (short*)d_ws;                       // 8 MB bf16 K
  short* vtr = kbf + (size_t)BB * SS * DD;         // 8 MB bf16 V^T
  cvt_k  <<<(BB*SS*DD/4)/256, 256, 0, stream>>>(k, kbf);
  trans_v<<<BB*(SS/32)*(DD/32), 256, 0, stream>>>(v, vtr);
  attn   <<<512, 512, 0, stream>>>(q, kbf, vtr, out);
}